// Round 1
// baseline (4612.785 us; speedup 1.0000x reference)
//
#include <hip/hip_runtime.h>
#include <hip/hip_bf16.h>
#include <math.h>

// ---------------- problem constants ----------------
#define DIMK   1024          // model dim, K of GEMM1
#define HEADS  16
#define DH     64
#define NQKV   3072          // 3 * INNER
#define SEQ    8192
#define BATCH  4
#define ROWS   (BATCH * SEQ) // 32768
#define EPSV   1e-6f

// ---------------- workspace layout (floats) --------
#define KV_ELEMS   (BATCH * HEADS * DH * DH)  // 262144  (1 MB)
#define KSUM_ELEMS (BATCH * HEADS * DH)       // 4096
#define Q_OFF      (KV_ELEMS + KSUM_ELEMS)    // 266240 floats (16B aligned)
// q_ws: ROWS*DIMK fp32 = 134.2 MB

__device__ __forceinline__ float elu1(float t) {
    // F.elu(x) + 1  ==  x+1 (x>0) else exp(x)
    return t > 0.0f ? t + 1.0f : expf(t);
}

// =====================================================================
// Kernel 1: qkv = x @ Wqkv (per head: 192 cols = q|k|v), feature maps,
//           q -> q_ws, partial kv = k^T v and ksum reduced per block,
//           atomicAdd into global kv / ksum.
// grid (ROWS/64, HEADS), block 256
// =====================================================================
__global__ __launch_bounds__(256) void k1_qkv(
    const float* __restrict__ x, const float* __restrict__ Wqkv,
    float* __restrict__ q_ws, float* __restrict__ kv, float* __restrict__ ksum)
{
    __shared__ float smem[8704];                       // 34.8 KB, aliased phases
    float (*sx)[20]  = (float(*)[20])smem;             // 64 x 16 (+pad), GEMM A
    float (*sw)[196] = (float(*)[196])(smem + 64*20);  // 16 x 192 (+pad), GEMM B
    float (*sA)[68]  = (float(*)[68])smem;             // phase2: q then k (64x64)
    float (*sB)[68]  = (float(*)[68])(smem + 64*68);   // phase2: v (64x64)

    const int t  = threadIdx.x;
    const int tx = t & 15;       // 0..15 -> 12 cols each
    const int ty = t >> 4;       // 0..15 -> 4 rows each
    const int row0 = blockIdx.x * 64;
    const int h    = blockIdx.y;
    const int b    = row0 / SEQ;

    float acc[4][12];
#pragma unroll
    for (int i = 0; i < 4; i++)
#pragma unroll
        for (int j = 0; j < 12; j++) acc[i][j] = 0.0f;

    const int xr  = t >> 2;          // 0..63
    const int xc4 = (t & 3) * 4;     // 0,4,8,12

    for (int k0 = 0; k0 < DIMK; k0 += 16) {
        // ---- stage x tile: 64x16, one float4 per thread
        {
            float4 xv = *(const float4*)(x + (size_t)(row0 + xr) * DIMK + k0 + xc4);
            *(float4*)&sx[xr][xc4] = xv;
        }
        // ---- stage W tile: 16x192, three float4 per thread
#pragma unroll
        for (int i = 0; i < 3; i++) {
            int idx = i * 256 + t;          // 0..767
            int kk  = idx / 48;             // 0..15
            int c   = (idx % 48) * 4;       // 0..188 local col
            int sec = c >> 6;               // 0=q,1=k,2=v
            int gcol = sec * 1024 + h * 64 + (c & 63);
            float4 wv = *(const float4*)(Wqkv + (size_t)(k0 + kk) * NQKV + gcol);
            *(float4*)&sw[kk][c] = wv;
        }
        __syncthreads();
#pragma unroll
        for (int kk = 0; kk < 16; kk++) {
            float a[4];
#pragma unroll
            for (int i = 0; i < 4; i++) a[i] = sx[ty * 4 + i][kk];
            float bv[12];
#pragma unroll
            for (int j4 = 0; j4 < 3; j4++) {
                float4 b4 = *(const float4*)&sw[kk][tx * 12 + j4 * 4];
                bv[j4*4+0] = b4.x; bv[j4*4+1] = b4.y; bv[j4*4+2] = b4.z; bv[j4*4+3] = b4.w;
            }
#pragma unroll
            for (int i = 0; i < 4; i++)
#pragma unroll
                for (int j = 0; j < 12; j++)
                    acc[i][j] = fmaf(a[i], bv[j], acc[i][j]);
        }
        __syncthreads();
    }

    // ---- phase 1: q(featured) -> sA, v(raw) -> sB
#pragma unroll
    for (int i = 0; i < 4; i++) {
        int r = ty * 4 + i;
#pragma unroll
        for (int j = 0; j < 12; j++) {
            int c = tx * 12 + j;
            float v = acc[i][j];
            if (c < 64)        sA[r][c]       = elu1(v);
            else if (c >= 128) sB[r][c - 128] = v;
        }
    }
    __syncthreads();
    // ---- cooperative coalesced q write: 1024 float4
#pragma unroll
    for (int i = 0; i < 4; i++) {
        int idx = i * 256 + t;
        int row = idx >> 4;
        int c4  = (idx & 15) * 4;
        *(float4*)(q_ws + (size_t)(row0 + row) * DIMK + h * 64 + c4) =
            *(const float4*)&sA[row][c4];
    }
    __syncthreads();
    // ---- phase 2: k(featured) -> sA
#pragma unroll
    for (int i = 0; i < 4; i++) {
        int r = ty * 4 + i;
#pragma unroll
        for (int j = 0; j < 12; j++) {
            int c = tx * 12 + j;
            if (c >= 64 && c < 128) sA[r][c - 64] = elu1(acc[i][j]);
        }
    }
    __syncthreads();
    // ---- kv partial: kv[d][f] += sum_r k[r][d] * v[r][f]; each thread 4x4
    {
        const int d0 = (t >> 4) * 4;
        const int f0 = (t & 15) * 4;
        float part[4][4];
#pragma unroll
        for (int i = 0; i < 4; i++)
#pragma unroll
            for (int j = 0; j < 4; j++) part[i][j] = 0.0f;
        for (int r = 0; r < 64; r++) {
            float4 a4 = *(const float4*)&sA[r][d0];
            float4 b4 = *(const float4*)&sB[r][f0];
            float av[4] = {a4.x, a4.y, a4.z, a4.w};
            float bw[4] = {b4.x, b4.y, b4.z, b4.w};
#pragma unroll
            for (int i = 0; i < 4; i++)
#pragma unroll
                for (int j = 0; j < 4; j++)
                    part[i][j] = fmaf(av[i], bw[j], part[i][j]);
        }
        float* kvp = kv + (size_t)(b * HEADS + h) * DH * DH;
#pragma unroll
        for (int i = 0; i < 4; i++)
#pragma unroll
            for (int j = 0; j < 4; j++)
                atomicAdd(kvp + (d0 + i) * DH + (f0 + j), part[i][j]);
    }
    // ---- ksum partial
    if (t < 64) {
        float s = 0.0f;
        for (int r = 0; r < 64; r++) s += sA[r][t];
        atomicAdd(ksum + (size_t)(b * HEADS + h) * DH + t, s);
    }
}

// =====================================================================
// Kernel 2: per head: A = (q @ kv) / (q . ksum + eps); out = A_all @ Wout + bout
// grid (ROWS/64, 1024/256), block 256
// =====================================================================
__global__ __launch_bounds__(256) void k2_out(
    const float* __restrict__ q_ws, const float* __restrict__ kv,
    const float* __restrict__ ksum, const float* __restrict__ Wout,
    const float* __restrict__ bout, float* __restrict__ out)
{
    __shared__ float sq [64][68];
    __shared__ float skv[64][68];
    __shared__ float sA [64][68];
    __shared__ float swt[16][260];
    __shared__ float sks[64];
    __shared__ float sden[64];

    const int t  = threadIdx.x;
    const int tx = t & 15;
    const int ty = t >> 4;
    const int row0 = blockIdx.x * 64;
    const int col0 = blockIdx.y * 256;
    const int b    = row0 / SEQ;

    float acc[4][16];
#pragma unroll
    for (int i = 0; i < 4; i++)
#pragma unroll
        for (int j = 0; j < 16; j++) acc[i][j] = 0.0f;

    for (int h = 0; h < HEADS; h++) {
        // ---- stage q slice (64x64) and kv (64x64), 4 float4 per thread each
#pragma unroll
        for (int i = 0; i < 4; i++) {
            int idx = i * 256 + t;
            int row = idx >> 4;
            int c4  = (idx & 15) * 4;
            *(float4*)&sq[row][c4] =
                *(const float4*)(q_ws + (size_t)(row0 + row) * DIMK + h * 64 + c4);
            *(float4*)&skv[row][c4] =
                *(const float4*)(kv + (size_t)(b * HEADS + h) * DH * DH + row * 64 + c4);
        }
        if (t < 64) sks[t] = ksum[(size_t)(b * HEADS + h) * DH + t];
        __syncthreads();
        // ---- denominators
        if (t < 64) {
            float s = 0.0f;
            for (int d = 0; d < 64; d++) s = fmaf(sq[t][d], sks[d], s);
            sden[t] = 1.0f / (s + EPSV);
        }
        __syncthreads();
        // ---- A = (sq @ skv) * den, each thread 4 rows x 4 cols
        {
            const int r0 = (t >> 4) * 4;
            const int f0 = (t & 15) * 4;
            float p[4][4];
#pragma unroll
            for (int i = 0; i < 4; i++)
#pragma unroll
                for (int j = 0; j < 4; j++) p[i][j] = 0.0f;
            for (int db = 0; db < 64; db += 4) {
                float4 kvv[4];
#pragma unroll
                for (int dd = 0; dd < 4; dd++)
                    kvv[dd] = *(const float4*)&skv[db + dd][f0];
#pragma unroll
                for (int i = 0; i < 4; i++) {
                    float4 q4 = *(const float4*)&sq[r0 + i][db];
                    p[i][0] = fmaf(q4.x, kvv[0].x, p[i][0]);
                    p[i][1] = fmaf(q4.x, kvv[0].y, p[i][1]);
                    p[i][2] = fmaf(q4.x, kvv[0].z, p[i][2]);
                    p[i][3] = fmaf(q4.x, kvv[0].w, p[i][3]);
                    p[i][0] = fmaf(q4.y, kvv[1].x, p[i][0]);
                    p[i][1] = fmaf(q4.y, kvv[1].y, p[i][1]);
                    p[i][2] = fmaf(q4.y, kvv[1].z, p[i][2]);
                    p[i][3] = fmaf(q4.y, kvv[1].w, p[i][3]);
                    p[i][0] = fmaf(q4.z, kvv[2].x, p[i][0]);
                    p[i][1] = fmaf(q4.z, kvv[2].y, p[i][1]);
                    p[i][2] = fmaf(q4.z, kvv[2].z, p[i][2]);
                    p[i][3] = fmaf(q4.z, kvv[2].w, p[i][3]);
                    p[i][0] = fmaf(q4.w, kvv[3].x, p[i][0]);
                    p[i][1] = fmaf(q4.w, kvv[3].y, p[i][1]);
                    p[i][2] = fmaf(q4.w, kvv[3].z, p[i][2]);
                    p[i][3] = fmaf(q4.w, kvv[3].w, p[i][3]);
                }
            }
#pragma unroll
            for (int i = 0; i < 4; i++) {
                float dr = sden[r0 + i];
#pragma unroll
                for (int j = 0; j < 4; j++) sA[r0 + i][f0 + j] = p[i][j] * dr;
            }
        }
        __syncthreads();
        // ---- accumulate C += A(64x64) @ Wout[h*64:+64, col0:+256]
        for (int ks = 0; ks < 4; ks++) {
#pragma unroll
            for (int i = 0; i < 4; i++) {
                int idx = i * 256 + t;
                int kk  = idx >> 6;
                int c4  = (idx & 63) * 4;
                *(float4*)&swt[kk][c4] =
                    *(const float4*)(Wout + (size_t)(h * 64 + ks * 16 + kk) * DIMK + col0 + c4);
            }
            __syncthreads();
#pragma unroll
            for (int kk = 0; kk < 16; kk++) {
                float a[4];
#pragma unroll
                for (int i = 0; i < 4; i++) a[i] = sA[ty * 4 + i][ks * 16 + kk];
#pragma unroll
                for (int g = 0; g < 4; g++) {
                    float4 b4 = *(const float4*)&swt[kk][tx * 4 + g * 64];
#pragma unroll
                    for (int i = 0; i < 4; i++) {
                        acc[i][g*4+0] = fmaf(a[i], b4.x, acc[i][g*4+0]);
                        acc[i][g*4+1] = fmaf(a[i], b4.y, acc[i][g*4+1]);
                        acc[i][g*4+2] = fmaf(a[i], b4.z, acc[i][g*4+2]);
                        acc[i][g*4+3] = fmaf(a[i], b4.w, acc[i][g*4+3]);
                    }
                }
            }
            __syncthreads();
        }
    }
    // ---- epilogue: + bout, write
#pragma unroll
    for (int i = 0; i < 4; i++) {
        int row = row0 + ty * 4 + i;
#pragma unroll
        for (int g = 0; g < 4; g++) {
            int col = col0 + tx * 4 + g * 64;
            float4 bo = *(const float4*)(bout + col);
            float4 o;
            o.x = acc[i][g*4+0] + bo.x;
            o.y = acc[i][g*4+1] + bo.y;
            o.z = acc[i][g*4+2] + bo.z;
            o.w = acc[i][g*4+3] + bo.w;
            *(float4*)(out + (size_t)row * DIMK + col) = o;
        }
    }
}

// =====================================================================
extern "C" void kernel_launch(void* const* d_in, const int* in_sizes, int n_in,
                              void* d_out, int out_size, void* d_ws, size_t ws_size,
                              hipStream_t stream) {
    const float* x    = (const float*)d_in[0];
    const float* Wqkv = (const float*)d_in[1];
    const float* Wout = (const float*)d_in[2];
    const float* bout = (const float*)d_in[3];
    float* out = (float*)d_out;

    float* ws   = (float*)d_ws;
    float* kv   = ws;                 // [B][H][64][64]
    float* ksum = ws + KV_ELEMS;      // [B][H][64]
    float* q_ws = ws + Q_OFF;         // [ROWS][1024]

    // zero the accumulators (harness poisons ws once; we must re-zero each call)
    hipMemsetAsync(d_ws, 0, (size_t)(KV_ELEMS + KSUM_ELEMS) * sizeof(float), stream);

    dim3 g1(ROWS / 64, HEADS);
    k1_qkv<<<g1, dim3(256), 0, stream>>>(x, Wqkv, q_ws, kv, ksum);

    dim3 g2(ROWS / 64, DIMK / 256);
    k2_out<<<g2, dim3(256), 0, stream>>>(q_ws, kv, ksum, Wout, bout, out);
}

// Round 2
// 727.071 us; speedup vs baseline: 6.3443x; 6.3443x over previous
//
#include <hip/hip_runtime.h>
#include <hip/hip_bf16.h>
#include <math.h>

// ---------------- problem constants ----------------
// x[4][8192][1024] fp32; Wqkv[1024][3072]; Wout[1024][1024]; bout[1024]
// processed per-batch (8192 rows) to fit workspace.

typedef unsigned short ushort_t;
typedef __attribute__((ext_vector_type(8))) short s8v;   // 8 bf16 (4 VGPRs) MFMA A/B frag
typedef __attribute__((ext_vector_type(4))) float f32x4; // MFMA C/D frag

#define MFMA(a,b,c) __builtin_amdgcn_mfma_f32_16x16x32_bf16((a),(b),(c),0,0,0)

__device__ __forceinline__ float bf2f(ushort_t u) {
    union { float f; unsigned v; } x; x.v = ((unsigned)u) << 16; return x.f;
}
__device__ __forceinline__ ushort_t f2bf(float f) {
    union { float f; unsigned v; } x; x.f = f;
    unsigned r = x.v + 0x7fffu + ((x.v >> 16) & 1u);   // RNE
    return (ushort_t)(r >> 16);
}
__device__ __forceinline__ float elu1(float t) { return t > 0.0f ? t + 1.0f : expf(t); }

// =====================================================================
// cast fp32 -> bf16, 8 elems/thread
// =====================================================================
__global__ void k_cast(const float* __restrict__ in, ushort_t* __restrict__ out, int n8) {
    int i = blockIdx.x * blockDim.x + threadIdx.x;
    if (i >= n8) return;
    const float4* p = (const float4*)in;
    float4 a = p[(size_t)i * 2], b = p[(size_t)i * 2 + 1];
    uint4 o;
    o.x = (unsigned)f2bf(a.x) | ((unsigned)f2bf(a.y) << 16);
    o.y = (unsigned)f2bf(a.z) | ((unsigned)f2bf(a.w) << 16);
    o.z = (unsigned)f2bf(b.x) | ((unsigned)f2bf(b.y) << 16);
    o.w = (unsigned)f2bf(b.z) | ((unsigned)f2bf(b.w) << 16);
    *(uint4*)(out + (size_t)i * 8) = o;
}

// =====================================================================
// transpose + cast: W[K][N] fp32 -> WT[N][K] bf16   (32x32 tiles)
// =====================================================================
__global__ __launch_bounds__(256) void k_transpose(const float* __restrict__ W,
                                                   ushort_t* __restrict__ WT, int K, int N) {
    __shared__ float s[32][33];
    const int t = threadIdx.x;
    const int k0 = blockIdx.x * 32, n0 = blockIdx.y * 32;
    const int kr = t >> 3, n4 = (t & 7) * 4;
    float4 v = *(const float4*)(W + (size_t)(k0 + kr) * N + n0 + n4);
    s[kr][n4 + 0] = v.x; s[kr][n4 + 1] = v.y; s[kr][n4 + 2] = v.z; s[kr][n4 + 3] = v.w;
    __syncthreads();
    const int nr = kr, k4 = n4;
    unsigned lo = (unsigned)f2bf(s[k4 + 0][nr]) | ((unsigned)f2bf(s[k4 + 1][nr]) << 16);
    unsigned hi = (unsigned)f2bf(s[k4 + 2][nr]) | ((unsigned)f2bf(s[k4 + 3][nr]) << 16);
    *(uint2*)(WT + (size_t)(n0 + nr) * K + k0 + k4) = make_uint2(lo, hi);
}

// =====================================================================
// MFMA GEMM: C[128x128] tile, A[M][1024] bf16 row-major, B=[N][1024] bf16 (W^T).
// 256 thr = 4 waves (2x2), 4x4 16x16x32 frags/wave, BK=32, reg-staged LDS.
// LDS row stride 40 ushort (80B): conflict-free ds_read_b128.
// MODE 0: epilogue elu1 on q,k sections -> qkv bf16 [M][3072]
// MODE 1: epilogue +bout -> out fp32 [M][1024]
// =====================================================================
template<int MODE>
__global__ __launch_bounds__(256) void k_gemm(
    const ushort_t* __restrict__ A, const ushort_t* __restrict__ B,
    ushort_t* __restrict__ obf, const float* __restrict__ bout, float* __restrict__ of)
{
    __shared__ ushort_t As[128 * 40];
    __shared__ ushort_t Bs[128 * 40];
    const int t = threadIdx.x, l = t & 63, w = t >> 6;
    const int wr = w >> 1, wc = w & 1;
    const int m0 = blockIdx.x * 128, n0 = blockIdx.y * 128;

    f32x4 acc[4][4];
    const f32x4 z = {0.f, 0.f, 0.f, 0.f};
#pragma unroll
    for (int i = 0; i < 4; i++)
#pragma unroll
        for (int j = 0; j < 4; j++) acc[i][j] = z;

    const int srow = t >> 2;          // 0..63
    const int sce  = (t & 3) * 8;     // k-elem 0,8,16,24
    const ushort_t* gA0 = A + (size_t)(m0 + srow) * 1024 + sce;
    const ushort_t* gA1 = A + (size_t)(m0 + 64 + srow) * 1024 + sce;
    const ushort_t* gB0 = B + (size_t)(n0 + srow) * 1024 + sce;
    const ushort_t* gB1 = B + (size_t)(n0 + 64 + srow) * 1024 + sce;
    const int wb = srow * 40 + sce;   // LDS elem idx (row stride 40)

    s8v ra0 = *(const s8v*)gA0, ra1 = *(const s8v*)gA1;
    s8v rb0 = *(const s8v*)gB0, rb1 = *(const s8v*)gB1;

    for (int kk = 0; kk < 32; kk++) {
        *(s8v*)&As[wb]        = ra0;
        *(s8v*)&As[wb + 2560] = ra1;
        *(s8v*)&Bs[wb]        = rb0;
        *(s8v*)&Bs[wb + 2560] = rb1;
        __syncthreads();
        if (kk < 31) {                 // prefetch next K-tile (overlaps MFMA below)
            int off = (kk + 1) * 32;
            ra0 = *(const s8v*)(gA0 + off); ra1 = *(const s8v*)(gA1 + off);
            rb0 = *(const s8v*)(gB0 + off); rb1 = *(const s8v*)(gB1 + off);
        }
        s8v af[4], bfr[4];
        const int cbE = (l >> 4) * 8;
#pragma unroll
        for (int mf = 0; mf < 4; mf++) {
            int r = wr * 64 + mf * 16 + (l & 15);
            af[mf] = *(const s8v*)&As[r * 40 + cbE];
        }
#pragma unroll
        for (int nf = 0; nf < 4; nf++) {
            int r = wc * 64 + nf * 16 + (l & 15);
            bfr[nf] = *(const s8v*)&Bs[r * 40 + cbE];
        }
#pragma unroll
        for (int mf = 0; mf < 4; mf++)
#pragma unroll
            for (int nf = 0; nf < 4; nf++)
                acc[mf][nf] = MFMA(af[mf], bfr[nf], acc[mf][nf]);
        __syncthreads();
    }

    if (MODE == 0) {
        const bool feat = (blockIdx.y >> 3) < 2;   // q,k sections get elu+1
#pragma unroll
        for (int mf = 0; mf < 4; mf++)
#pragma unroll
            for (int nf = 0; nf < 4; nf++)
#pragma unroll
                for (int r = 0; r < 4; r++) {
                    int row = m0 + wr * 64 + mf * 16 + (l >> 4) * 4 + r;
                    int col = n0 + wc * 64 + nf * 16 + (l & 15);
                    float v = acc[mf][nf][r];
                    obf[(size_t)row * 3072 + col] = f2bf(feat ? elu1(v) : v);
                }
    } else {
#pragma unroll
        for (int mf = 0; mf < 4; mf++)
#pragma unroll
            for (int nf = 0; nf < 4; nf++) {
                int col = n0 + wc * 64 + nf * 16 + (l & 15);
                float bo = bout[col];
#pragma unroll
                for (int r = 0; r < 4; r++) {
                    int row = m0 + wr * 64 + mf * 16 + (l >> 4) * 4 + r;
                    of[(size_t)row * 1024 + col] = acc[mf][nf][r] + bo;
                }
            }
    }
}

// =====================================================================
// kv[h][f][d] += sum_n k_feat[n][d] * v[n][f]   (stored TRANSPOSED: kvT[f][d])
// ksum[h][d]  += sum_n k_feat[n][d]
// grid (16 heads, 16 n-splits of 512), 256 thr / 4 waves (2x2 over 64x64 C).
// k,v staged transposed into LDS [d][128n] / [f][128n], stride 136 (272B).
// =====================================================================
#define KST 136
__global__ __launch_bounds__(256) void k_kv(
    const ushort_t* __restrict__ qkv, float* __restrict__ kv, float* __restrict__ ksum)
{
    __shared__ ushort_t kT[64 * KST];
    __shared__ ushort_t vT[64 * KST];
    __shared__ float ksl[64];
    const int t = threadIdx.x, l = t & 63, w = t >> 6;
    const int wr = w >> 1, wc = w & 1;
    const int h = blockIdx.x;
    const int n00 = blockIdx.y * 512;
    const f32x4 z = {0.f, 0.f, 0.f, 0.f};
    f32x4 acc[2][2] = {{z, z}, {z, z}};
    float ksloc[4] = {0.f, 0.f, 0.f, 0.f};
    const int sd0 = (t & 15) * 4;
    if (t < 64) ksl[t] = 0.f;

    for (int c = 0; c < 4; c++) {
        __syncthreads();
        const int n0 = n00 + c * 128;
#pragma unroll
        for (int i = 0; i < 8; i++) {
            int n = i * 16 + (t >> 4);
            const ushort_t* kp = qkv + (size_t)(n0 + n) * 3072 + 1024 + h * 64 + sd0;
            ushort4 kw = *(const ushort4*)kp;
            ushort4 vw = *(const ushort4*)(kp + 1024);
            ksloc[0] += bf2f(kw.x); ksloc[1] += bf2f(kw.y);
            ksloc[2] += bf2f(kw.z); ksloc[3] += bf2f(kw.w);
            kT[(sd0 + 0) * KST + n] = kw.x; kT[(sd0 + 1) * KST + n] = kw.y;
            kT[(sd0 + 2) * KST + n] = kw.z; kT[(sd0 + 3) * KST + n] = kw.w;
            vT[(sd0 + 0) * KST + n] = vw.x; vT[(sd0 + 1) * KST + n] = vw.y;
            vT[(sd0 + 2) * KST + n] = vw.z; vT[(sd0 + 3) * KST + n] = vw.w;
        }
        __syncthreads();
#pragma unroll
        for (int kb = 0; kb < 128; kb += 32) {
            s8v af[2], bfr[2];
#pragma unroll
            for (int ma = 0; ma < 2; ma++) {
                int d = wr * 32 + ma * 16 + (l & 15);
                af[ma] = *(const s8v*)&kT[d * KST + kb + (l >> 4) * 8];
            }
#pragma unroll
            for (int fb = 0; fb < 2; fb++) {
                int f = wc * 32 + fb * 16 + (l & 15);
                bfr[fb] = *(const s8v*)&vT[f * KST + kb + (l >> 4) * 8];
            }
#pragma unroll
            for (int ma = 0; ma < 2; ma++)
#pragma unroll
                for (int fb = 0; fb < 2; fb++)
                    acc[ma][fb] = MFMA(af[ma], bfr[fb], acc[ma][fb]);
        }
    }
    atomicAdd(&ksl[sd0 + 0], ksloc[0]); atomicAdd(&ksl[sd0 + 1], ksloc[1]);
    atomicAdd(&ksl[sd0 + 2], ksloc[2]); atomicAdd(&ksl[sd0 + 3], ksloc[3]);
    __syncthreads();
    if (t < 64) atomicAdd(&ksum[h * 64 + t], ksl[t]);
#pragma unroll
    for (int ma = 0; ma < 2; ma++)
#pragma unroll
        for (int fb = 0; fb < 2; fb++)
#pragma unroll
            for (int r = 0; r < 4; r++) {
                int d = wr * 32 + ma * 16 + (l >> 4) * 4 + r;
                int f = wc * 32 + fb * 16 + (l & 15);
                atomicAdd(&kv[h * 4096 + f * 64 + d], acc[ma][fb][r]);
            }
}

// =====================================================================
// den[row][h] = 1 / (sum_d q[row][h*64+d] * ksum[h][d] + eps)
// =====================================================================
__global__ void k_den(const ushort_t* __restrict__ qkv, const float* __restrict__ ksum,
                      float* __restrict__ den) {
    int idx = blockIdx.x * 256 + threadIdx.x;      // 8192*16
    int row = idx >> 4, h = idx & 15;
    const ushort_t* qp = qkv + (size_t)row * 3072 + h * 64;
    const float* ks = ksum + h * 64;
    float s = 0.f;
#pragma unroll
    for (int j = 0; j < 16; j++) {
        ushort4 u = *(const ushort4*)(qp + j * 4);
        s += bf2f(u.x) * ks[j * 4 + 0] + bf2f(u.y) * ks[j * 4 + 1]
           + bf2f(u.z) * ks[j * 4 + 2] + bf2f(u.w) * ks[j * 4 + 3];
    }
    den[idx] = 1.f / (s + 1e-6f);
}

// =====================================================================
// attn[row][h*64+f] = (sum_d q[row][h*64+d] * kv[h][d][f]) * den[row][h]
// grid (8192/32 row-tiles, 2 h-halves), 256 thr / 4 waves; wave = 32rows x 16f.
// kvT[f][d] fp32 staged -> LDS bf16 [f][64d] stride 72 (144B).
// =====================================================================
#define AST 72
__global__ __launch_bounds__(256) void k_apply(
    const ushort_t* __restrict__ qkv, const float* __restrict__ kv,
    const float* __restrict__ den, ushort_t* __restrict__ attn)
{
    __shared__ ushort_t kvb[64 * AST];
    const int t = threadIdx.x, l = t & 63, w = t >> 6;
    const int row0 = blockIdx.x * 32;
    const f32x4 z = {0.f, 0.f, 0.f, 0.f};

    for (int hh = 0; hh < 8; hh++) {
        const int h = blockIdx.y * 8 + hh;
        __syncthreads();
        {   // stage kvT (fp32 -> bf16): thread t covers f=t>>2, d0=(t&3)*16
            const int f = t >> 2, d0 = (t & 3) * 16;
            const float* src = kv + h * 4096 + f * 64 + d0;
            s8v v0, v1;
#pragma unroll
            for (int j = 0; j < 8; j++) {
                v0[j] = (short)f2bf(src[j]);
                v1[j] = (short)f2bf(src[j + 8]);
            }
            *(s8v*)&kvb[f * AST + d0]     = v0;
            *(s8v*)&kvb[f * AST + d0 + 8] = v1;
        }
        __syncthreads();
        f32x4 acc[2] = {z, z};
#pragma unroll
        for (int ks = 0; ks < 2; ks++) {
            const int f = w * 16 + (l & 15);
            s8v bfr = *(const s8v*)&kvb[f * AST + ks * 32 + (l >> 4) * 8];
#pragma unroll
            for (int ma = 0; ma < 2; ma++) {
                int row = row0 + ma * 16 + (l & 15);
                s8v afr = *(const s8v*)(qkv + (size_t)row * 3072 + h * 64 + ks * 32 + (l >> 4) * 8);
                acc[ma] = MFMA(afr, bfr, acc[ma]);
            }
        }
#pragma unroll
        for (int ma = 0; ma < 2; ma++)
#pragma unroll
            for (int r = 0; r < 4; r++) {
                int row = row0 + ma * 16 + (l >> 4) * 4 + r;
                float dv = den[row * 16 + h];
                int f = w * 16 + (l & 15);
                attn[(size_t)row * 1024 + h * 64 + f] = f2bf(acc[ma][r] * dv);
            }
    }
}

// =====================================================================
// workspace layout (bytes), total ~94.4 MB (fits the >=135MB proven pool):
//  0        WqkvT  [3072][1024] bf16  6291456
//  6291456  WoutT  [1024][1024] bf16  2097152
//  8388608  kv     [16][64][64] f32   1048576   (kvT[f][d], zeroed per b)
//  9437184  ksum   [16][64] f32       16384     (zeroed per b)
//  9453568  den    [8192][16] f32     524288
//  10485760 xb     [8192][1024] bf16  16777216
//  27262976 qkv    [8192][3072] bf16  50331648
//  77594624 attn   [8192][1024] bf16  16777216
// =====================================================================
extern "C" void kernel_launch(void* const* d_in, const int* in_sizes, int n_in,
                              void* d_out, int out_size, void* d_ws, size_t ws_size,
                              hipStream_t stream) {
    const float* x    = (const float*)d_in[0];
    const float* Wqkv = (const float*)d_in[1];
    const float* Wout = (const float*)d_in[2];
    const float* bout = (const float*)d_in[3];
    float* out = (float*)d_out;
    char* ws = (char*)d_ws;

    ushort_t* WqkvT = (ushort_t*)(ws + 0);
    ushort_t* WoutT = (ushort_t*)(ws + 6291456);
    float*    kv    = (float*)(ws + 8388608);
    float*    ksum  = (float*)(ws + 9437184);
    float*    den   = (float*)(ws + 9453568);
    ushort_t* xb    = (ushort_t*)(ws + 10485760);
    ushort_t* qkv   = (ushort_t*)(ws + 27262976);
    ushort_t* attn  = (ushort_t*)(ws + 77594624);

    k_transpose<<<dim3(32, 96), 256, 0, stream>>>(Wqkv, WqkvT, 1024, 3072);
    k_transpose<<<dim3(32, 32), 256, 0, stream>>>(Wout, WoutT, 1024, 1024);

    for (int b = 0; b < 4; b++) {
        const float* xsrc = x + (size_t)b * 8192 * 1024;
        k_cast<<<4096, 256, 0, stream>>>(xsrc, xb, 1048576);
        hipMemsetAsync(kv, 0, 1048576 + 16384, stream);   // kv + ksum
        k_gemm<0><<<dim3(64, 24), 256, 0, stream>>>(xb, WqkvT, qkv, nullptr, nullptr);
        k_kv<<<dim3(16, 16), 256, 0, stream>>>(qkv, kv, ksum);
        k_den<<<512, 256, 0, stream>>>(qkv, ksum, den);
        k_apply<<<dim3(256, 2), 256, 0, stream>>>(qkv, kv, den, attn);
        k_gemm<1><<<dim3(64, 8), 256, 0, stream>>>(attn, WoutT, nullptr, bout,
                                                   out + (size_t)b * 8192 * 1024);
    }
}